// Round 1
// baseline (1617.642 us; speedup 1.0000x reference)
//
#include <hip/hip_runtime.h>
#include <math.h>

// Problem constants (GNN gated-graph layer: B=64, N=27, C=512, L=2, fp32)
#define NN 27
#define NE 729           // N*N
#define CC 512
#define BB 64
#define EPSV 1e-5f

#define XROWS (BB*NN)    // 1728 node rows
#define EROWS (BB*NE)    // 46656 edge rows

// ---------------- fp32 TN GEMM: out = A @ W^T (+ optional edge epilogue) ----
// A: [M, 512] row-major, W: [512, 512] row-major.
// mode 0: out[row*ldo + ncol_off + col] = acc
// mode 1: out[row*512 + col] = acc + xW[axrow*2048+col] + xW[bxrow*2048+512+col]
//         (edge message m = A(x)[i] + B(x)[j] + edge@We^T)
#define BMT 128
#define BNT 128
#define BKT 32
#define LDT (BMT + 4)    // +4 floats pad: keeps 16B alignment, breaks bank stride

__global__ __launch_bounds__(256)
void gemm_tn(const float* __restrict__ A, const float* __restrict__ W,
             float* __restrict__ out, int M, int ldo, int ncol_off,
             const float* __restrict__ xW, int mode)
{
    __shared__ float As[BKT][LDT];   // transposed: As[k][m]
    __shared__ float Ws[BKT][LDT];   // transposed: Ws[k][n]

    const int bm = blockIdx.x * BMT;
    const int bn = blockIdx.y * BNT;
    const int t  = threadIdx.x;
    const int tx = t & 15;           // 16x16 thread grid
    const int ty = t >> 4;
    const int gi = t & 7;            // 16B granule column 0..7 (covers BK=32)
    const int r0 = t >> 3;           // 0..31

    float acc[8][8];
    #pragma unroll
    for (int i = 0; i < 8; ++i)
        #pragma unroll
        for (int j = 0; j < 8; ++j) acc[i][j] = 0.f;

    for (int kt = 0; kt < CC; kt += BKT) {
        #pragma unroll
        for (int i = 0; i < 4; ++i) {
            int row  = r0 + i * 32;              // 0..127
            int grow = bm + row;
            float4 va = make_float4(0.f, 0.f, 0.f, 0.f);
            if (grow < M) va = *(const float4*)&A[(size_t)grow * CC + kt + gi * 4];
            As[gi*4+0][row] = va.x;
            As[gi*4+1][row] = va.y;
            As[gi*4+2][row] = va.z;
            As[gi*4+3][row] = va.w;
            float4 vw = *(const float4*)&W[(size_t)(bn + row) * CC + kt + gi * 4];
            Ws[gi*4+0][row] = vw.x;
            Ws[gi*4+1][row] = vw.y;
            Ws[gi*4+2][row] = vw.z;
            Ws[gi*4+3][row] = vw.w;
        }
        __syncthreads();
        #pragma unroll 4
        for (int k = 0; k < BKT; ++k) {
            float a[8], b[8];
            *(float4*)&a[0] = *(const float4*)&As[k][ty * 4];
            *(float4*)&a[4] = *(const float4*)&As[k][64 + ty * 4];
            *(float4*)&b[0] = *(const float4*)&Ws[k][tx * 4];
            *(float4*)&b[4] = *(const float4*)&Ws[k][64 + tx * 4];
            #pragma unroll
            for (int i = 0; i < 8; ++i)
                #pragma unroll
                for (int j = 0; j < 8; ++j)
                    acc[i][j] = fmaf(a[i], b[j], acc[i][j]);
        }
        __syncthreads();
    }

    #pragma unroll
    for (int ii = 0; ii < 8; ++ii) {
        int row = bm + ty * 4 + (ii & 3) + (ii >> 2) * 64;
        if (row >= M) continue;
        if (mode == 0) {
            float* o = out + (size_t)row * ldo + ncol_off + bn;
            *(float4*)&o[tx * 4]      = *(float4*)&acc[ii][0];
            *(float4*)&o[64 + tx * 4] = *(float4*)&acc[ii][4];
        } else {
            int b  = row / NE;
            int e  = row - b * NE;
            int i2 = e / NN;
            int j2 = e - i2 * NN;
            const float* axp = xW + (size_t)(b * NN + i2) * 2048 + bn;        // A(x) cols 0..511
            const float* bxp = xW + (size_t)(b * NN + j2) * 2048 + 512 + bn;  // B(x) cols 512..1023
            float* o = out + (size_t)row * 512 + bn;
            #pragma unroll
            for (int h = 0; h < 2; ++h) {
                int off = h * 64 + tx * 4;
                float4 av = *(const float4*)&axp[off];
                float4 bv = *(const float4*)&bxp[off];
                float4 r;
                r.x = acc[ii][h*4+0] + av.x + bv.x;
                r.y = acc[ii][h*4+1] + av.y + bv.y;
                r.z = acc[ii][h*4+2] + av.z + bv.z;
                r.w = acc[ii][h*4+3] + av.w + bv.w;
                *(float4*)&o[off] = r;
            }
        }
    }
}

// ---------------- BatchNorm stats over (batch, C) per channel --------------
// src logical layout [BB][nch][CC]; one block per channel; outputs affine
// ka = rstd*w, kb = bias - mean*ka so apply is a single fma.
__global__ __launch_bounds__(256)
void bn_stats(const float* __restrict__ src, int nch,
              const float* __restrict__ w, const float* __restrict__ bias,
              float* __restrict__ ka, float* __restrict__ kb)
{
    const int ch = blockIdx.x;
    const int t  = threadIdx.x;
    const int sub = t >> 7;            // 0..1 (two b-rows in flight)
    const int cf  = (t & 127) * 4;     // float4 column

    float s = 0.f, sq = 0.f;
    for (int b = 0; b < BB; b += 2) {
        const float* p = src + ((size_t)(b + sub) * nch + ch) * CC + cf;
        float4 v = *(const float4*)p;
        s  += v.x + v.y + v.z + v.w;
        sq += v.x*v.x + v.y*v.y + v.z*v.z + v.w*v.w;
    }
    // wave reduce
    #pragma unroll
    for (int off = 32; off; off >>= 1) {
        s  += __shfl_down(s, off);
        sq += __shfl_down(sq, off);
    }
    __shared__ float red[2][4];
    const int wid = t >> 6, lane = t & 63;
    if (lane == 0) { red[0][wid] = s; red[1][wid] = sq; }
    __syncthreads();
    if (t == 0) {
        s  = red[0][0] + red[0][1] + red[0][2] + red[0][3];
        sq = red[1][0] + red[1][1] + red[1][2] + red[1][3];
        const float inv = 1.f / (float)(BB * CC);
        float mean = s * inv;
        float var  = sq * inv - mean * mean;
        float r    = rsqrtf(var + EPSV);
        float kaw  = r * w[ch];
        ka[ch] = kaw;
        kb[ch] = bias[ch] - mean * kaw;
    }
}

// ---------------- edge residual update: eout = ein + relu(bn(m)) -----------
__global__ __launch_bounds__(256)
void edge_update(const float* __restrict__ m, const float* __restrict__ ein,
                 float* __restrict__ eout,
                 const float* __restrict__ ka, const float* __restrict__ kb)
{
    const size_t idx = (size_t)blockIdx.x * blockDim.x + threadIdx.x; // float4 idx
    const size_t total = (size_t)BB * NE * CC / 4;
    if (idx >= total) return;
    const int e = (int)((idx >> 7) % NE);     // idx/128 % 729
    const float a = ka[e], b = kb[e];
    float4 mv = ((const float4*)m)[idx];
    float4 ev = ((const float4*)ein)[idx];
    float4 o;
    o.x = ev.x + fmaxf(fmaf(mv.x, a, b), 0.f);
    o.y = ev.y + fmaxf(fmaf(mv.y, a, b), 0.f);
    o.z = ev.z + fmaxf(fmaf(mv.z, a, b), 0.f);
    o.w = ev.w + fmaxf(fmaf(mv.w, a, b), 0.f);
    ((float4*)eout)[idx] = o;
}

// ---------------- fused sigmoid -> softmax(j) -> aggregate -----------------
// one block per (b,i); thread per channel c. 27 j-values held in registers.
// xpre[b,i,c] = U(x)[b,i,c] + (1/27) * sum_j softmax_j(exp(sig(edge))) * V(x)[b,j,c]
__global__ __launch_bounds__(512)
void agg_kernel(const float* __restrict__ edge, const float* __restrict__ xW,
                float* __restrict__ xpre)
{
    const int bi = blockIdx.x;          // b*27 + i
    const int c  = threadIdx.x;         // 0..511
    const int b  = bi / NN;
    const int i  = bi - b * NN;

    const float* ebase = edge + ((size_t)b * NE + (size_t)i * NN) * CC + c;
    float ex[NN];
    float den = 0.f;
    #pragma unroll
    for (int j = 0; j < NN; ++j) {
        float sv  = ebase[(size_t)j * CC];
        float sig = 1.f / (1.f + __expf(-sv));
        float e   = __expf(sig);
        ex[j] = e;
        den  += e;
    }
    float accv = 0.f;
    const float* vbase = xW + (size_t)(b * NN) * 2048 + 1024 + c;  // V(x) cols
    #pragma unroll
    for (int j = 0; j < NN; ++j)
        accv = fmaf(ex[j], vbase[(size_t)j * 2048], accv);

    float u = xW[(size_t)bi * 2048 + 1536 + c];                    // U(x) cols
    xpre[(size_t)bi * CC + c] = u + accv / (den * (float)NN);
}

// ---------------- node residual update: xout = xpre + relu(bn(xpre)) -------
__global__ __launch_bounds__(256)
void x_update(const float* __restrict__ xpre, float* __restrict__ xout,
              const float* __restrict__ ka, const float* __restrict__ kb)
{
    const int idx = blockIdx.x * blockDim.x + threadIdx.x;   // float4 idx
    const int total = XROWS * CC / 4;                        // 221184
    if (idx >= total) return;
    const int i = (idx >> 7) % NN;
    const float a = ka[i], b = kb[i];
    float4 v = ((const float4*)xpre)[idx];
    float4 o;
    o.x = v.x + fmaxf(fmaf(v.x, a, b), 0.f);
    o.y = v.y + fmaxf(fmaf(v.y, a, b), 0.f);
    o.z = v.z + fmaxf(fmaf(v.z, a, b), 0.f);
    o.w = v.w + fmaxf(fmaf(v.w, a, b), 0.f);
    ((float4*)xout)[idx] = o;
}

// ---------------------------------------------------------------------------
extern "C" void kernel_launch(void* const* d_in, const int* in_sizes, int n_in,
                              void* d_out, int out_size, void* d_ws, size_t ws_size,
                              hipStream_t stream)
{
    const float* x0   = (const float*)d_in[0];
    const float* e0   = (const float*)d_in[1];
    const float* Wu   = (const float*)d_in[2];
    const float* Wv   = (const float*)d_in[3];
    const float* Wa   = (const float*)d_in[4];
    const float* Wb   = (const float*)d_in[5];
    const float* We   = (const float*)d_in[6];
    const float* bnvw = (const float*)d_in[7];
    const float* bnvb = (const float*)d_in[8];
    const float* bnew = (const float*)d_in[9];
    const float* bneb = (const float*)d_in[10];

    const size_t XSZ = (size_t)XROWS * CC;     // 884736
    const size_t ESZ = (size_t)EROWS * CC;     // 23887872

    float* xout = (float*)d_out;               // x result
    float* eout = xout + XSZ;                  // edge result

    // workspace layout (floats): xW[1728][2048] | m[46656][512] | xpre | ka/kb
    float* ws   = (float*)d_ws;
    float* xW   = ws;                          // A|B|V|U concatenated columns
    float* m    = xW + (size_t)XROWS * 2048;
    float* xpre = m + ESZ;
    float* ka_e = xpre + XSZ;
    float* kb_e = ka_e + NE;
    float* ka_v = kb_e + NE;
    float* kb_v = ka_v + NN;

    const dim3 gN((XROWS + BMT - 1) / BMT, CC / BNT);   // 14 x 4
    const dim3 gE((EROWS + BMT - 1) / BMT, CC / BNT);   // 365 x 4

    for (int l = 0; l < 2; ++l) {
        const float* xi = l ? (const float*)xout : x0;
        const float* ei = l ? (const float*)eout : e0;
        const size_t wof = (size_t)l * CC * CC;

        // node projections -> xW columns [A|B|V|U]
        gemm_tn<<<gN, 256, 0, stream>>>(xi, Wa + wof, xW, XROWS, 2048, 0,    nullptr, 0);
        gemm_tn<<<gN, 256, 0, stream>>>(xi, Wb + wof, xW, XROWS, 2048, 512,  nullptr, 0);
        gemm_tn<<<gN, 256, 0, stream>>>(xi, Wv + wof, xW, XROWS, 2048, 1024, nullptr, 0);
        gemm_tn<<<gN, 256, 0, stream>>>(xi, Wu + wof, xW, XROWS, 2048, 1536, nullptr, 0);

        // edge message m = A(x)[i] + B(x)[j] + edge @ We^T  (fused epilogue)
        gemm_tn<<<gE, 256, 0, stream>>>(ei, We + wof, m, EROWS, CC, 0, xW, 1);

        // edge BN + residual
        bn_stats<<<NE, 256, 0, stream>>>(m, NE, bnew + (size_t)l * NE, bneb + (size_t)l * NE, ka_e, kb_e);
        edge_update<<<(int)(ESZ / 4 / 256), 256, 0, stream>>>(m, ei, eout, ka_e, kb_e);

        // sigmoid -> softmax(j) -> aggregate -> + U(x)
        agg_kernel<<<XROWS, 512, 0, stream>>>(eout, xW, xpre);

        // node BN + residual
        bn_stats<<<NN, 256, 0, stream>>>(xpre, NN, bnvw + (size_t)l * NN, bnvb + (size_t)l * NN, ka_v, kb_v);
        x_update<<<(int)(XSZ / 4 / 256), 256, 0, stream>>>(xpre, xout, ka_v, kb_v);
    }
}

// Round 2
// 571.957 us; speedup vs baseline: 2.8283x; 2.8283x over previous
//
#include <hip/hip_runtime.h>
#include <math.h>

// GNN gated-graph layer: B=64, N=27, C=512, L=2, fp32 in/out, bf16 MFMA GEMMs
#define NN 27
#define NE 729
#define CC 512
#define BB 64
#define EPSV 1e-5f

#define XROWS (BB*NN)    // 1728
#define EROWS (BB*NE)    // 46656

typedef short s16x8 __attribute__((ext_vector_type(8)));   // 8 bf16 (4 VGPRs)
typedef float f32x4 __attribute__((ext_vector_type(4)));
typedef unsigned short bfu_t;

typedef const __attribute__((address_space(1))) void gv_t;
typedef __attribute__((address_space(3))) void lv_t;

static __device__ __forceinline__ bfu_t f2bu(float f) {
    __bf16 h = (__bf16)f;                       // RNE
    return __builtin_bit_cast(unsigned short, h);
}

// ---------------- fp32 -> bf16 convert (8 elems/thread) ---------------------
__global__ __launch_bounds__(256)
void f2b(const float* __restrict__ src, bfu_t* __restrict__ dst, int n)
{
    int i = (blockIdx.x * 256 + threadIdx.x) * 8;
    if (i >= n) return;
    float4 a = *(const float4*)(src + i);
    float4 b = *(const float4*)(src + i + 4);
    s16x8 v;
    v[0] = (short)f2bu(a.x); v[1] = (short)f2bu(a.y);
    v[2] = (short)f2bu(a.z); v[3] = (short)f2bu(a.w);
    v[4] = (short)f2bu(b.x); v[5] = (short)f2bu(b.y);
    v[6] = (short)f2bu(b.z); v[7] = (short)f2bu(b.w);
    *(s16x8*)(dst + i) = v;
}

// ---------------- bf16 MFMA GEMM: out = A @ W^T  ---------------------------
// A: [M,512] bf16 row-major. W: [rows,512] bf16 row-major (rows indexed by n).
// mode 0: out[row*ldo + bn + col] = acc                       (node proj -> xW)
// mode 1: out[row*512 + col] = acc + Ax[i][col] + Bx[j][col]  (edge message m)
// 128x128 tile, BK=32, 4 waves, 16x16x32 MFMA, global_load_lds staging.
__global__ __launch_bounds__(256)
void gemm_mfma(const bfu_t* __restrict__ A, const bfu_t* __restrict__ W,
               float* __restrict__ out, int M, int ldo,
               const float* __restrict__ xW, int mode)
{
    __shared__ bfu_t As[128 * 32];     // [row][k], 64B rows, 8 KB
    __shared__ bfu_t Bs[128 * 32];

    const int t    = threadIdx.x;
    const int lane = t & 63;
    const int w    = t >> 6;
    const int bm   = blockIdx.x * 128;
    const int bn   = blockIdx.y * 128;
    const int wr   = (w >> 1) * 64;    // wave's 64x64 sub-tile
    const int wc   = (w & 1) * 64;

    f32x4 acc[4][4];
    #pragma unroll
    for (int i = 0; i < 4; ++i)
        #pragma unroll
        for (int j = 0; j < 4; ++j) acc[i][j] = (f32x4){0.f, 0.f, 0.f, 0.f};

    // staging map: wave chunk c covers rows [(w*2+c)*16, +16); lane -> row + kquad
    const int r0 = w * 32 + (lane >> 2);
    const int r1 = r0 + 16;
    const int kc = (lane & 3) * 8;
    int ga0 = bm + r0; if (ga0 > M - 1) ga0 = M - 1;   // clamp OOB rows
    int ga1 = bm + r1; if (ga1 > M - 1) ga1 = M - 1;
    const bfu_t* a0 = A + (size_t)ga0 * CC + kc;
    const bfu_t* a1 = A + (size_t)ga1 * CC + kc;
    const bfu_t* w0 = W + (size_t)(bn + r0) * CC + kc;
    const bfu_t* w1 = W + (size_t)(bn + r1) * CC + kc;
    bfu_t* lA0 = As + (w * 2 + 0) * 512;
    bfu_t* lA1 = As + (w * 2 + 1) * 512;
    bfu_t* lB0 = Bs + (w * 2 + 0) * 512;
    bfu_t* lB1 = Bs + (w * 2 + 1) * 512;

    // fragment read map: row = base + frag*16 + (lane&15), k = (lane>>4)*8
    const int fra = wr + (lane & 15);
    const int frb = wc + (lane & 15);
    const int fk  = (lane >> 4) * 8;

    for (int kt = 0; kt < CC; kt += 32) {
        if (kt) __syncthreads();
        __builtin_amdgcn_global_load_lds((gv_t*)(a0 + kt), (lv_t*)lA0, 16, 0, 0);
        __builtin_amdgcn_global_load_lds((gv_t*)(a1 + kt), (lv_t*)lA1, 16, 0, 0);
        __builtin_amdgcn_global_load_lds((gv_t*)(w0 + kt), (lv_t*)lB0, 16, 0, 0);
        __builtin_amdgcn_global_load_lds((gv_t*)(w1 + kt), (lv_t*)lB1, 16, 0, 0);
        __syncthreads();

        s16x8 af[4], bfg[4];
        #pragma unroll
        for (int i = 0; i < 4; ++i)
            af[i] = *(const s16x8*)&As[(fra + i * 16) * 32 + fk];
        #pragma unroll
        for (int i = 0; i < 4; ++i)
            bfg[i] = *(const s16x8*)&Bs[(frb + i * 16) * 32 + fk];
        #pragma unroll
        for (int i = 0; i < 4; ++i)
            #pragma unroll
            for (int j = 0; j < 4; ++j)
                acc[i][j] = __builtin_amdgcn_mfma_f32_16x16x32_bf16(af[i], bfg[j], acc[i][j], 0, 0, 0);
    }

    // C/D layout: col = lane&15, row = (lane>>4)*4 + q
    const int crb = wr + ((lane >> 4) << 2);
    const int ccb = wc + (lane & 15);
    if (mode == 0) {
        #pragma unroll
        for (int mi = 0; mi < 4; ++mi) {
            #pragma unroll
            for (int q = 0; q < 4; ++q) {
                int row = bm + crb + mi * 16 + q;
                if (row >= M) continue;
                float* o = out + (size_t)row * ldo + bn + ccb;
                #pragma unroll
                for (int ni = 0; ni < 4; ++ni) o[ni * 16] = acc[mi][ni][q];
            }
        }
    } else {
        #pragma unroll
        for (int mi = 0; mi < 4; ++mi) {
            #pragma unroll
            for (int q = 0; q < 4; ++q) {
                int row = bm + crb + mi * 16 + q;
                if (row >= M) continue;
                int b  = row / NE;
                int e  = row - b * NE;
                int i2 = e / NN;
                int j2 = e - i2 * NN;
                const float* axp = xW + (size_t)(b * NN + i2) * 2048 + bn + ccb;
                const float* bxp = xW + (size_t)(b * NN + j2) * 2048 + 512 + bn + ccb;
                float* o = out + (size_t)row * CC + bn + ccb;
                #pragma unroll
                for (int ni = 0; ni < 4; ++ni)
                    o[ni * 16] = acc[mi][ni][q] + axp[ni * 16] + bxp[ni * 16];
            }
        }
    }
}

// ---------------- BatchNorm stats per channel ------------------------------
__global__ __launch_bounds__(256)
void bn_stats(const float* __restrict__ src, int nch,
              const float* __restrict__ w, const float* __restrict__ bias,
              float* __restrict__ ka, float* __restrict__ kb)
{
    const int ch = blockIdx.x;
    const int t  = threadIdx.x;
    const int sub = t >> 7;
    const int cf  = (t & 127) * 4;

    float s = 0.f, sq = 0.f;
    for (int b = 0; b < BB; b += 2) {
        const float* p = src + ((size_t)(b + sub) * nch + ch) * CC + cf;
        float4 v = *(const float4*)p;
        s  += v.x + v.y + v.z + v.w;
        sq += v.x*v.x + v.y*v.y + v.z*v.z + v.w*v.w;
    }
    #pragma unroll
    for (int off = 32; off; off >>= 1) {
        s  += __shfl_down(s, off);
        sq += __shfl_down(sq, off);
    }
    __shared__ float red[2][4];
    const int wid = t >> 6, lane = t & 63;
    if (lane == 0) { red[0][wid] = s; red[1][wid] = sq; }
    __syncthreads();
    if (t == 0) {
        s  = red[0][0] + red[0][1] + red[0][2] + red[0][3];
        sq = red[1][0] + red[1][1] + red[1][2] + red[1][3];
        const float inv = 1.f / (float)(BB * CC);
        float mean = s * inv;
        float var  = sq * inv - mean * mean;
        float r    = rsqrtf(var + EPSV);
        float kaw  = r * w[ch];
        ka[ch] = kaw;
        kb[ch] = bias[ch] - mean * kaw;
    }
}

// ---------------- edge update: eout = ein + relu(bn(m)), + bf16 copy -------
__global__ __launch_bounds__(256)
void edge_update(const float* __restrict__ m, const float* __restrict__ ein,
                 float* __restrict__ eout, bfu_t* __restrict__ ebf,
                 const float* __restrict__ ka, const float* __restrict__ kb)
{
    const size_t idx = (size_t)blockIdx.x * blockDim.x + threadIdx.x;
    const size_t total = (size_t)EROWS * CC / 4;
    if (idx >= total) return;
    const int e = (int)((idx >> 7) % NE);
    const float a = ka[e], b = kb[e];
    float4 mv = ((const float4*)m)[idx];
    float4 ev = ((const float4*)ein)[idx];
    float4 o;
    o.x = ev.x + fmaxf(fmaf(mv.x, a, b), 0.f);
    o.y = ev.y + fmaxf(fmaf(mv.y, a, b), 0.f);
    o.z = ev.z + fmaxf(fmaf(mv.z, a, b), 0.f);
    o.w = ev.w + fmaxf(fmaf(mv.w, a, b), 0.f);
    ((float4*)eout)[idx] = o;
    ushort4 h;
    h.x = f2bu(o.x); h.y = f2bu(o.y); h.z = f2bu(o.z); h.w = f2bu(o.w);
    ((ushort4*)ebf)[idx] = h;
}

// ---------------- fused sigmoid -> softmax(j) -> aggregate -----------------
__global__ __launch_bounds__(512)
void agg_kernel(const float* __restrict__ edge, const float* __restrict__ xW,
                float* __restrict__ xpre)
{
    const int bi = blockIdx.x;
    const int c  = threadIdx.x;
    const int b  = bi / NN;
    const int i  = bi - b * NN;

    const float* ebase = edge + ((size_t)b * NE + (size_t)i * NN) * CC + c;
    float ex[NN];
    float den = 0.f;
    #pragma unroll
    for (int j = 0; j < NN; ++j) {
        float sv  = ebase[(size_t)j * CC];
        float sig = 1.f / (1.f + __expf(-sv));
        float e   = __expf(sig);
        ex[j] = e;
        den  += e;
    }
    float accv = 0.f;
    const float* vbase = xW + (size_t)(b * NN) * 2048 + 1024 + c;
    #pragma unroll
    for (int j = 0; j < NN; ++j)
        accv = fmaf(ex[j], vbase[(size_t)j * 2048], accv);

    float u = xW[(size_t)bi * 2048 + 1536 + c];
    xpre[(size_t)bi * CC + c] = u + accv / (den * (float)NN);
}

// ---------------- node update: xout = xpre + relu(bn(xpre)), + bf16 copy ---
__global__ __launch_bounds__(256)
void x_update(const float* __restrict__ xpre, float* __restrict__ xout,
              bfu_t* __restrict__ xbf,
              const float* __restrict__ ka, const float* __restrict__ kb)
{
    const int idx = blockIdx.x * blockDim.x + threadIdx.x;
    const int total = XROWS * CC / 4;
    if (idx >= total) return;
    const int i = (idx >> 7) % NN;
    const float a = ka[i], b = kb[i];
    float4 v = ((const float4*)xpre)[idx];
    float4 o;
    o.x = v.x + fmaxf(fmaf(v.x, a, b), 0.f);
    o.y = v.y + fmaxf(fmaf(v.y, a, b), 0.f);
    o.z = v.z + fmaxf(fmaf(v.z, a, b), 0.f);
    o.w = v.w + fmaxf(fmaf(v.w, a, b), 0.f);
    ((float4*)xout)[idx] = o;
    ushort4 h;
    h.x = f2bu(o.x); h.y = f2bu(o.y); h.z = f2bu(o.z); h.w = f2bu(o.w);
    ((ushort4*)xbf)[idx] = h;
}

// ---------------------------------------------------------------------------
extern "C" void kernel_launch(void* const* d_in, const int* in_sizes, int n_in,
                              void* d_out, int out_size, void* d_ws, size_t ws_size,
                              hipStream_t stream)
{
    const float* x0   = (const float*)d_in[0];
    const float* e0   = (const float*)d_in[1];
    const float* Wu   = (const float*)d_in[2];
    const float* Wv   = (const float*)d_in[3];
    const float* Wa   = (const float*)d_in[4];
    const float* Wb   = (const float*)d_in[5];
    const float* We   = (const float*)d_in[6];
    const float* bnvw = (const float*)d_in[7];
    const float* bnvb = (const float*)d_in[8];
    const float* bnew = (const float*)d_in[9];
    const float* bneb = (const float*)d_in[10];

    const size_t XSZ = (size_t)XROWS * CC;     // 884736
    const size_t ESZ = (size_t)EROWS * CC;     // 23887872
    const int    WSZ = CC * CC;                // 262144

    float* xout = (float*)d_out;
    float* eout = xout + XSZ;

    // fp32 workspace
    float* ws   = (float*)d_ws;
    float* xW   = ws;                          // [1728][2048]  A|B|V|U cols
    float* m    = xW + (size_t)XROWS * 2048;
    float* xpre = m + ESZ;
    float* ka_e = xpre + XSZ;
    float* kb_e = ka_e + NE;
    float* ka_v = kb_e + NE;
    float* kb_v = ka_v + NN;
    // bf16 workspace (after fp32 area)
    bfu_t* bws  = (bfu_t*)(ka_v + 2048);
    bfu_t* ebf  = bws;                                     // [46656][512]
    bfu_t* xbf  = ebf + ESZ;                               // [1728][512]
    bfu_t* WnB  = xbf + XSZ;                               // [L][2048][512]
    bfu_t* WeB  = WnB + (size_t)2 * 2048 * CC;             // [L][512][512]

    // ---- weight converts (both layers, concat node weights A|B|V|U) ----
    const int wgrid = WSZ / 8 / 256;   // 128
    for (int l = 0; l < 2; ++l) {
        bfu_t* nb = WnB + (size_t)l * 2048 * CC;
        f2b<<<wgrid, 256, 0, stream>>>(Wa + (size_t)l * WSZ, nb,            WSZ);
        f2b<<<wgrid, 256, 0, stream>>>(Wb + (size_t)l * WSZ, nb + WSZ,      WSZ);
        f2b<<<wgrid, 256, 0, stream>>>(Wv + (size_t)l * WSZ, nb + 2 * WSZ,  WSZ);
        f2b<<<wgrid, 256, 0, stream>>>(Wu + (size_t)l * WSZ, nb + 3 * WSZ,  WSZ);
        f2b<<<wgrid, 256, 0, stream>>>(We + (size_t)l * WSZ, WeB + (size_t)l * WSZ, WSZ);
    }

    const dim3 gN(14, 16);    // node: M=1728, N=2048
    const dim3 gE(365, 4);    // edge: M=46656, N=512

    for (int l = 0; l < 2; ++l) {
        const float* ei = l ? (const float*)eout : e0;
        if (l == 0) {
            f2b<<<(int)(XSZ / 8 / 256), 256, 0, stream>>>(x0, xbf, (int)XSZ);
            f2b<<<(int)(ESZ / 8 / 256), 256, 0, stream>>>(e0, ebf, (int)ESZ);
        }

        // node projections -> xW [1728][2048]
        gemm_mfma<<<gN, 256, 0, stream>>>(xbf, WnB + (size_t)l * 2048 * CC,
                                          xW, XROWS, 2048, nullptr, 0);
        // edge message m = edge @ We^T + A(x)[i] + B(x)[j]
        gemm_mfma<<<gE, 256, 0, stream>>>(ebf, WeB + (size_t)l * WSZ,
                                          m, EROWS, CC, xW, 1);

        bn_stats<<<NE, 256, 0, stream>>>(m, NE, bnew + (size_t)l * NE,
                                         bneb + (size_t)l * NE, ka_e, kb_e);
        edge_update<<<(int)(ESZ / 4 / 256), 256, 0, stream>>>(m, ei, eout, ebf, ka_e, kb_e);

        agg_kernel<<<XROWS, 512, 0, stream>>>(eout, xW, xpre);

        bn_stats<<<NN, 256, 0, stream>>>(xpre, NN, bnvw + (size_t)l * NN,
                                         bnvb + (size_t)l * NN, ka_v, kb_v);
        x_update<<<(int)(XSZ / 4 / 256), 256, 0, stream>>>(xpre, xout, xbf, ka_v, kb_v);
    }
}